// Round 1
// baseline (616.182 us; speedup 1.0000x reference)
//
#include <hip/hip_runtime.h>

#define SEQ   2048
#define BATCH 4096
#define HD    32

// ---------------- fast device math ----------------
__device__ __forceinline__ float exp2_fast(float a) {
#if __has_builtin(__builtin_amdgcn_exp2f)
    return __builtin_amdgcn_exp2f(a);
#else
    return exp2f(a);
#endif
}

__device__ __forceinline__ float rcp_fast(float a) {
#if __has_builtin(__builtin_amdgcn_rcpf)
    return __builtin_amdgcn_rcpf(a);
#else
    return 1.0f / a;
#endif
}

// tanh(x) = sign(x) * (1 - e^{-2|x|}) / (1 + e^{-2|x|}),  e^{-2|x|} = 2^{-2*log2(e)*|x|}
__device__ __forceinline__ float fast_tanh(float v) {
    float ax = fabsf(v);
    float e  = exp2_fast(ax * -2.8853900817779268f);
    float r  = (1.0f - e) * rcp_fast(1.0f + e);
    return copysignf(r, v);
}

// DPP helper: returns shifted/broadcast lane value within rows, 0 where no source.
template <int CTRL>
__device__ __forceinline__ float dpp_mov0(float v) {
    return __int_as_float(
        __builtin_amdgcn_update_dpp(0, __float_as_int(v), CTRL, 0xF, 0xF, false));
}

// ds_swizzle xor-16 within each 32-lane half: lane receives value of lane^16.
__device__ __forceinline__ float swz_xor16(float v) {
    return __int_as_float(__builtin_amdgcn_ds_swizzle(__float_as_int(v), 0x401F));
}

// ---------------- kernel ----------------
// 32 lanes per batch element (2 elements per wave, 8 per block, 8 waves/CU).
// Lane s: half = s>>4 selects the h k-slice [half*16, half*16+16); q = s&15.
// Lane accumulates rows 2q and 2q+1 over its 16-element h slice; the partner
// lane (s^16) holds the complementary slice. Each lane finalizes row 2q+half:
// the missing half-dot arrives via one ds_swizzle (both lanes export the
// partial of the row they do NOT own). LDS read traffic per CU is unchanged
// vs the 16-lane version (4x ds_read_b128/lane), but waves/SIMD doubles 1->2.
__global__ __launch_bounds__(256, 2) void rnn_elman_kernel(
    const float* __restrict__ x, const float* __restrict__ hidden,
    const float* __restrict__ W_ih, const float* __restrict__ b_ih,
    const float* __restrict__ W_hh, const float* __restrict__ b_hh,
    const float* __restrict__ W_fc, const float* __restrict__ b_fc,
    float* __restrict__ out)
{
    __shared__ float sh[8 * 36];     // 8 elements/block, padded stride 36 floats

    const int tid   = threadIdx.x;
    const int s     = tid & 31;       // lane within element group
    const int half  = s >> 4;         // k-slice half
    const int q     = s & 15;
    const int eb    = tid >> 5;       // element within block (0..7)
    const int e     = blockIdx.x * 8 + eb;
    const int r_own = 2 * q + half;       // row this lane finalizes
    const int r_oth = 2 * q + 1 - half;   // partner's row

    // ---- weights into registers (16-element K-slices of two rows) ----
    float4 wo[4], wn[4];
    {
        const float4* WO = reinterpret_cast<const float4*>(W_hh + r_own * HD + half * 16);
        const float4* WN = reinterpret_cast<const float4*>(W_hh + r_oth * HD + half * 16);
        #pragma unroll
        for (int k = 0; k < 4; ++k) { wo[k] = WO[k]; wn[k] = WN[k]; }
    }
    const float wih  = W_ih[r_own];
    const float bias = b_ih[r_own] + b_hh[r_own];
    const float wfc  = W_fc[r_own];
    const float bfc  = b_fc[0];

    float* slot = sh + eb * 36;
    const float4* rd = reinterpret_cast<const float4*>(slot + half * 16);

    // ---- init hidden state into LDS ----
    slot[r_own] = hidden[e * HD + r_own];
    __builtin_amdgcn_wave_barrier();

    float4 hb[4];
    #pragma unroll
    for (int k = 0; k < 4; ++k) hb[k] = rd[k];

    // ---- x prefetch pipe (distance 4) ----
    float xq0 = x[0 * BATCH + e];
    float xq1 = x[1 * BATCH + e];
    float xq2 = x[2 * BATCH + e];
    float xq3 = x[3 * BATCH + e];

    #pragma unroll 4
    for (int t = 0; t < SEQ; ++t) {
        const float xv = xq0;
        xq0 = xq1; xq1 = xq2; xq2 = xq3;
        {
            int tt = t + 4; tt = tt < SEQ - 1 ? tt : SEQ - 1;   // clamped, in bounds
            xq3 = x[tt * BATCH + e];
        }

        // ---- half-dots: 4 independent FMA chains of depth 8 ----
        float a0 = fmaf(xv, wih, bias);   // own row, first 8 of slice
        float a1 = 0.f;                   // own row, last 8 of slice
        float b0 = 0.f, b1 = 0.f;         // other row
        #pragma unroll
        for (int k = 0; k < 2; ++k) {
            const float4 h4 = hb[k];
            const float4 h5 = hb[k + 2];
            const float4 u  = wo[k];
            const float4 v  = wo[k + 2];
            const float4 m  = wn[k];
            const float4 n  = wn[k + 2];
            a0 = fmaf(u.x, h4.x, a0);
            a0 = fmaf(u.y, h4.y, a0);
            a0 = fmaf(u.z, h4.z, a0);
            a0 = fmaf(u.w, h4.w, a0);
            a1 = fmaf(v.x, h5.x, a1);
            a1 = fmaf(v.y, h5.y, a1);
            a1 = fmaf(v.z, h5.z, a1);
            a1 = fmaf(v.w, h5.w, a1);
            b0 = fmaf(m.x, h4.x, b0);
            b0 = fmaf(m.y, h4.y, b0);
            b0 = fmaf(m.z, h4.z, b0);
            b0 = fmaf(m.w, h4.w, b0);
            b1 = fmaf(n.x, h5.x, b1);
            b1 = fmaf(n.y, h5.y, b1);
            b1 = fmaf(n.z, h5.z, b1);
            b1 = fmaf(n.w, h5.w, b1);
        }
        const float own = a0 + a1;                 // my half of my row (seeded)
        const float oth = b0 + b1;                 // my half of partner's row
        const float z   = own + swz_xor16(oth);    // partner sends my missing half
        const float h   = fast_tanh(z);

        // ---- publish own h, refetch this lane's k-slice for next step ----
        slot[r_own] = h;
        __builtin_amdgcn_wave_barrier();
        #pragma unroll
        for (int k = 0; k < 4; ++k) hb[k] = rd[k];

        // ---- output projection: reduce 32 lanes via DPP ----
        float p = h * wfc;
        p += dpp_mov0<0x111>(p);   // row_shr:1
        p += dpp_mov0<0x112>(p);   // row_shr:2
        p += dpp_mov0<0x114>(p);   // row_shr:4
        p += dpp_mov0<0x118>(p);   // row_shr:8  -> lanes 15/31/47/63 hold row sums
        p += dpp_mov0<0x142>(p);   // row_bcast15 -> lanes 31/63 hold full 32-lane sums
        if (s == 31) out[t * BATCH + e] = p + bfc;
    }
}

// ---------------- launch ----------------
extern "C" void kernel_launch(void* const* d_in, const int* in_sizes, int n_in,
                              void* d_out, int out_size, void* d_ws, size_t ws_size,
                              hipStream_t stream) {
    const float* x    = (const float*)d_in[0];
    const float* hid  = (const float*)d_in[1];
    const float* W_ih = (const float*)d_in[2];
    const float* b_ih = (const float*)d_in[3];
    const float* W_hh = (const float*)d_in[4];
    const float* b_hh = (const float*)d_in[5];
    const float* W_fc = (const float*)d_in[6];
    const float* b_fc = (const float*)d_in[7];
    float* out = (float*)d_out;

    dim3 grid(BATCH / 8);    // 512 blocks -> 2 blocks/CU
    dim3 block(256);         // 8 elements/block, 4 waves; 8 waves/CU total
    rnn_elman_kernel<<<grid, block, 0, stream>>>(x, hid, W_ih, b_ih, W_hh, b_hh,
                                                 W_fc, b_fc, out);
}

// Round 2
// 609.443 us; speedup vs baseline: 1.0111x; 1.0111x over previous
//
#include <hip/hip_runtime.h>

#define SEQ   2048
#define BATCH 4096
#define HD    32

// ---------------- fast device math ----------------
__device__ __forceinline__ float exp2_fast(float a) {
#if __has_builtin(__builtin_amdgcn_exp2f)
    return __builtin_amdgcn_exp2f(a);
#else
    return exp2f(a);
#endif
}

__device__ __forceinline__ float rcp_fast(float a) {
#if __has_builtin(__builtin_amdgcn_rcpf)
    return __builtin_amdgcn_rcpf(a);
#else
    return 1.0f / a;
#endif
}

// tanh(x) = sign(x) * (1 - e^{-2|x|}) / (1 + e^{-2|x|}),  e^{-2|x|} = 2^{-2*log2(e)*|x|}
__device__ __forceinline__ float fast_tanh(float v) {
    float ax = fabsf(v);
    float e  = exp2_fast(ax * -2.8853900817779268f);
    float r  = (1.0f - e) * rcp_fast(1.0f + e);
    return copysignf(r, v);
}

// DPP exchange helper (all lanes active; xor-pattern ctrls => no OOB reads).
// 0xB1: quad_perm [1,0,3,2]  = xor-1
// 0x4E: quad_perm [2,3,0,1]  = xor-2
// 0x141: row_half_mirror     = xor-7  (within 8)
// 0x140: row_mirror          = xor-15 (within 16)
template <int CTRL>
__device__ __forceinline__ float dpp_x(float v) {
    return __int_as_float(
        __builtin_amdgcn_update_dpp(0, __float_as_int(v), CTRL, 0xF, 0xF, false));
}

// ds_swizzle xor-16 within each 32-lane half: lane receives value of lane^16.
__device__ __forceinline__ float swz_xor16(float v) {
    return __int_as_float(__builtin_amdgcn_ds_swizzle(__float_as_int(v), 0x401F));
}

// ---------------- kernel ----------------
// 32 contiguous lanes per batch element (2 elements/wave, 8/block, 8 waves/CU).
// Lane i (0..31): ks = i&3 selects k-slice [ks*8, ks*8+8); lane accumulates 4 rows
//   row_j = (i&~3) | ((i&3)^j), j=0..3, over its 8-element h slice (32 FMAs).
// The xor-row-permutation makes the cross-slice reduce uniform: every lane keeps
// p0,p2 and sends p1,p3; z(row i) = (p0 + qp1(p1)) + qp2(p2 + qp1(p3)) -- 6 VALU
// ops, no LDS in the recurrence-critical reduce. h state in LDS only for the
// 8-float broadcast (2x ds_read_b128/lane, half the prior DS volume).
__global__ __launch_bounds__(256, 2) void rnn_elman_kernel(
    const float* __restrict__ x, const float* __restrict__ hidden,
    const float* __restrict__ W_ih, const float* __restrict__ b_ih,
    const float* __restrict__ W_hh, const float* __restrict__ b_hh,
    const float* __restrict__ W_fc, const float* __restrict__ b_fc,
    float* __restrict__ out)
{
    __shared__ float sh[8 * 36];     // 8 elements/block, padded stride 36 floats

    const int tid = threadIdx.x;
    const int i   = tid & 31;        // lane within element group == owned row
    const int ks  = i & 3;           // k-slice index
    const int eb  = tid >> 5;        // element within block (0..7)
    const int e   = blockIdx.x * 8 + eb;

    // ---- weights into registers: 4 xor-permuted rows x 8-k slice ----
    float w0[8], w1[8], w2[8], w3[8];
    {
        const int rbase = i & ~3;
        const float* R0 = W_hh + (rbase | (ks ^ 0)) * HD + ks * 8;
        const float* R1 = W_hh + (rbase | (ks ^ 1)) * HD + ks * 8;
        const float* R2 = W_hh + (rbase | (ks ^ 2)) * HD + ks * 8;
        const float* R3 = W_hh + (rbase | (ks ^ 3)) * HD + ks * 8;
        #pragma unroll
        for (int m = 0; m < 8; ++m) {
            w0[m] = R0[m]; w1[m] = R1[m]; w2[m] = R2[m]; w3[m] = R3[m];
        }
    }
    const float wih  = W_ih[i];
    const float bias = b_ih[i] + b_hh[i];
    const float wfc  = W_fc[i];
    const float bfc  = b_fc[0];

    float* slot = sh + eb * 36;
    const float4* rd = reinterpret_cast<const float4*>(slot + ks * 8);

    // ---- init hidden state into LDS, pull my k-slice ----
    slot[i] = hidden[e * HD + i];
    __builtin_amdgcn_wave_barrier();
    float4 hb0 = rd[0], hb1 = rd[1];

    // ---- x prefetch pipe (distance 4), scalar-marched row base ----
    float xq0 = x[(size_t)0 * BATCH + e];
    float xq1 = x[(size_t)1 * BATCH + e];
    float xq2 = x[(size_t)2 * BATCH + e];
    float xq3 = x[(size_t)3 * BATCH + e];

    #pragma unroll 4
    for (int t = 0; t < SEQ; ++t) {
        const float xv = xq0;
        xq0 = xq1; xq1 = xq2; xq2 = xq3;
        {
            int tt = t + 4; tt = tt < SEQ ? tt : SEQ - 1;    // uniform clamp (SALU)
            const float* xr = x + (size_t)tt * BATCH;         // uniform row base
            xq3 = xr[e];
        }

        // ---- partials: 4 independent FMA chains of depth 8/9 ----
        float p0 = fmaf(xv, wih, bias);   // row i seed rides in p0's chain
        float p1 = 0.f, p2 = 0.f, p3 = 0.f;
        {
            const float* hv0 = reinterpret_cast<const float*>(&hb0);
            const float* hv1 = reinterpret_cast<const float*>(&hb1);
            #pragma unroll
            for (int m = 0; m < 4; ++m) {
                const float ha = hv0[m];
                const float hc = hv1[m];
                p0 = fmaf(w0[m], ha, p0);
                p1 = fmaf(w1[m], ha, p1);
                p2 = fmaf(w2[m], ha, p2);
                p3 = fmaf(w3[m], ha, p3);
                p0 = fmaf(w0[m + 4], hc, p0);
                p1 = fmaf(w1[m + 4], hc, p1);
                p2 = fmaf(w2[m + 4], hc, p2);
                p3 = fmaf(w3[m + 4], hc, p3);
            }
        }

        // ---- cross-slice reduce: lane i ends with full z for row i ----
        const float q0 = p0 + dpp_x<0xB1>(p1);   // xor-1
        const float q1 = p2 + dpp_x<0xB1>(p3);   // xor-1
        const float z  = q0 + dpp_x<0x4E>(q1);   // xor-2
        const float h  = fast_tanh(z);

        // ---- publish own h, refetch k-slice early (latency hides under out) ----
        slot[i] = h;
        __builtin_amdgcn_wave_barrier();
        hb0 = rd[0]; hb1 = rd[1];

        // ---- output projection: 32-lane all-xor sum (DS swizzle off hot path) ----
        float u = h * wfc;
        u += dpp_x<0xB1>(u);     // xor-1
        u += dpp_x<0x4E>(u);     // xor-2
        u += dpp_x<0x141>(u);    // xor-7 (row_half_mirror)
        u += dpp_x<0x140>(u);    // xor-15 (row_mirror)
        u += swz_xor16(u);       // xor-16 -> all 32 lanes hold the total
        if ((tid & 31) == 0) {
            float* orow = out + (size_t)t * BATCH;            // uniform row base
            orow[e] = u + bfc;
        }
    }
}

// ---------------- launch ----------------
extern "C" void kernel_launch(void* const* d_in, const int* in_sizes, int n_in,
                              void* d_out, int out_size, void* d_ws, size_t ws_size,
                              hipStream_t stream) {
    const float* x    = (const float*)d_in[0];
    const float* hid  = (const float*)d_in[1];
    const float* W_ih = (const float*)d_in[2];
    const float* b_ih = (const float*)d_in[3];
    const float* W_hh = (const float*)d_in[4];
    const float* b_hh = (const float*)d_in[5];
    const float* W_fc = (const float*)d_in[6];
    const float* b_fc = (const float*)d_in[7];
    float* out = (float*)d_out;

    dim3 grid(BATCH / 8);    // 512 blocks -> 2 blocks/CU
    dim3 block(256);         // 8 elements/block, 4 waves; 8 waves/CU, 2/SIMD
    rnn_elman_kernel<<<grid, block, 0, stream>>>(x, hid, W_ih, b_ih, W_hh, b_hh,
                                                 W_fc, b_fc, out);
}